// Round 7
// baseline (265.385 us; speedup 1.0000x reference)
//
#include <hip/hip_runtime.h>
#include <math.h>

#define B_    32
#define CIN_  256
#define HW_   784
#define H_    28
#define W_    28
#define COUT_ 256
#define KEXP_ 4
#define HID_  64

typedef short short8 __attribute__((ext_vector_type(8)));
typedef unsigned short ushort4v __attribute__((ext_vector_type(4)));
typedef float floatx16 __attribute__((ext_vector_type(16)));

__device__ __forceinline__ unsigned short f2bf(float f) {
    union { float f; unsigned int u; } v; v.f = f;
    unsigned int r = (v.u + 0x7FFFu + ((v.u >> 16) & 1u)) >> 16;
    return (unsigned short)r;
}

// ---------------- Kernel 1: transpose + partial pool ----------------
__global__ __launch_bounds__(256) void xpose_pool_kernel(const float* __restrict__ x,
                                                         unsigned short* __restrict__ x_t,
                                                         float* __restrict__ partial) {
    __shared__ float tile[32][33];
    int bid = blockIdx.x;              // 32 * 8 * 25
    int b   = bid / 200;
    int rem = bid - b * 200;
    int icg = rem / 25;
    int pxt = rem % 25;
    int ic0 = icg * 32;
    int px0 = pxt * 32;
    int t = threadIdx.x;
    int c = t & 31, rr = t >> 5;
    #pragma unroll
    for (int r = 0; r < 4; ++r) {
        int icr = rr + r * 8;
        int px = px0 + c;
        float v = (px < HW_) ? x[((size_t)(b * CIN_ + ic0 + icr)) * HW_ + px] : 0.f;
        tile[icr][c] = v;
    }
    __syncthreads();
    #pragma unroll
    for (int r = 0; r < 4; ++r) {
        int pxr = rr + r * 8;
        int px = px0 + pxr;
        if (px < HW_)
            x_t[((size_t)b * HW_ + px) * CIN_ + ic0 + c] = f2bf(tile[c][pxr]);
    }
    if (t < 32) {
        float s = 0.f;
        #pragma unroll
        for (int cc = 0; cc < 32; ++cc) s += tile[t][cc];
        partial[((size_t)b * 25 + pxt) * CIN_ + ic0 + t] = s * (1.0f / HW_);
    }
}

// ---------------- Kernel 2: SE first layer only -> h[b][64] ----------------
__global__ __launch_bounds__(256) void se_h_kernel(const float* __restrict__ partial,
                                                   const float* __restrict__ fc1_w,
                                                   float* __restrict__ h_g) {
    __shared__ float pl[CIN_];
    __shared__ float wb[64 * 257];
    int b = blockIdx.x, t = threadIdx.x;
    {
        float s = 0.f;
        for (int pt = 0; pt < 25; ++pt)
            s += partial[((size_t)b * 25 + pt) * CIN_ + t];
        pl[t] = s;
    }
    #pragma unroll
    for (int i = 0; i < 16; ++i) {
        int l = t + i * 256;                 // float4 index over 64x256
        float4 v = *(const float4*)(fc1_w + (size_t)l * 4);
        int r = l >> 6, cc = (l & 63) * 4;
        float* dst = &wb[r * 257 + cc];
        dst[0] = v.x; dst[1] = v.y; dst[2] = v.z; dst[3] = v.w;
    }
    __syncthreads();
    if (t < HID_) {
        float s = 0.f;
        const float* wr = &wb[t * 257];
        for (int c = 0; c < CIN_; ++c) s += pl[c] * wr[c];
        h_g[b * HID_ + t] = fmaxf(s, 0.f);
    }
}

// ---------------- Kernel 3: fc2 + softmax + aggregate -> agg[b][rs][oc][ic] ----------------
// grid = 512: oc = bid&255, b0 = (bid>>8)*16
__global__ __launch_bounds__(256) void agg5_kernel(const float* __restrict__ weight,
                                                   const float* __restrict__ h_g,
                                                   const float* __restrict__ fc2_w,
                                                   const float* __restrict__ fc2_b,
                                                   unsigned short* __restrict__ agg) {
    __shared__ float ws_w[KEXP_ * CIN_ * 9];   // [k][rs][ic] : k*2304 + rs*256 + ic
    __shared__ float f2s[KEXP_ * HID_];        // [k][j]
    __shared__ float hb[16 * 65];              // [bq][j] pad 65
    __shared__ float pb[KEXP_ * 16];           // [k][bq]
    int bid = blockIdx.x;
    int oc = bid & 255;
    int b0 = (bid >> 8) * 16;
    int t = threadIdx.x;

    // stage expert weights, transposed to [k][rs][ic]
    #pragma unroll
    for (int i = 0; i < 9; ++i) {
        int e4 = t + i * 256;                  // float4 index over 9216 floats
        int k = e4 / 576;
        int r4 = e4 - k * 576;
        float4 v = *(const float4*)(weight + (size_t)k * 589824 + (size_t)oc * 2304 + (size_t)r4 * 4);
        int f = r4 * 4;
        #pragma unroll
        for (int q = 0; q < 4; ++q) {
            int ic = (f + q) / 9, rs = (f + q) - ic * 9;
            ws_w[k * 2304 + rs * 256 + ic] = ((const float*)&v)[q];
        }
    }
    // stage fc2 rows for this oc and h for 16 samples
    {
        int k = t >> 6, j = t & 63;
        f2s[t] = fc2_w[((size_t)(k * COUT_ + oc)) * HID_ + j];
    }
    #pragma unroll
    for (int i = 0; i < 4; ++i) {
        int l = t + i * 256;
        if (l < 16 * HID_) {
            int bq = l >> 6, j = l & 63;
            hb[bq * 65 + j] = h_g[(size_t)(b0 + bq) * HID_ + j];
        }
    }
    __syncthreads();
    // fc2 + softmax: t<64 -> bq = t>>2, k = t&3
    if (t < 64) {
        int bq = t >> 2, k = t & 3;
        float s = fc2_b[k * COUT_ + oc];
        const float* hr = &hb[bq * 65];
        const float* fr = &f2s[k * HID_];
        #pragma unroll
        for (int j = 0; j < HID_; ++j) s += hr[j] * fr[j];
        float y = s * 0.125f;
        float m1 = fmaxf(y, __shfl_xor(y, 1));
        float m  = fmaxf(m1, __shfl_xor(m1, 2));
        float e = expf(y - m);
        float s1 = e + __shfl_xor(e, 1);
        float sm = s1 + __shfl_xor(s1, 2);
        pb[k * 16 + bq] = e / sm;
    }
    __syncthreads();

    int icg = t & 63, blane = t >> 6;
    for (int rs = 0; rs < 9; ++rs) {
        float4 w0 = *(const float4*)&ws_w[0 * 2304 + rs * 256 + icg * 4];
        float4 w1 = *(const float4*)&ws_w[1 * 2304 + rs * 256 + icg * 4];
        float4 w2 = *(const float4*)&ws_w[2 * 2304 + rs * 256 + icg * 4];
        float4 w3 = *(const float4*)&ws_w[3 * 2304 + rs * 256 + icg * 4];
        #pragma unroll
        for (int bb = 0; bb < 4; ++bb) {
            int bidx = blane * 4 + bb;
            float p0 = pb[0 * 16 + bidx], p1 = pb[1 * 16 + bidx];
            float p2 = pb[2 * 16 + bidx], p3 = pb[3 * 16 + bidx];
            ushort4v pack;
            pack[0] = f2bf(p0 * w0.x + p1 * w1.x + p2 * w2.x + p3 * w3.x);
            pack[1] = f2bf(p0 * w0.y + p1 * w1.y + p2 * w2.y + p3 * w3.y);
            pack[2] = f2bf(p0 * w0.z + p1 * w1.z + p2 * w2.z + p3 * w3.z);
            pack[3] = f2bf(p0 * w0.w + p1 * w1.w + p2 * w2.w + p3 * w3.w);
            *(ushort4v*)(agg + (((size_t)(b0 + bidx) * 9 + rs) * COUT_ + oc) * CIN_ + icg * 4) = pack;
        }
    }
}

// ---------------- Kernel 4: MFMA conv, 64oc x 7row blocks, 2 blocks/CU ----------------
// grid = 512: b = gid&31, ocq = (gid>>5)&3, rowblk = gid>>7 (0..3), py0 = rowblk*7
// waves: wo = w&1 (oc 32-group), wr = w>>1 (rows 0-3 / 4-6)
__global__ __launch_bounds__(256, 2) void conv_mfma5_kernel(const unsigned short* __restrict__ x_t,
                                                            const unsigned short* __restrict__ agg,
                                                            float* __restrict__ out) {
    __shared__ __align__(16) short Xs[9 * 35 * 72];   // 45360 B

    int gid = blockIdx.x;
    int b      = gid & 31;
    int ocq    = (gid >> 5) & 3;
    int rowblk = gid >> 7;
    int py0 = rowblk * 7;

    int t = threadIdx.x;
    int lane = t & 63, w = t >> 6;
    int wo = w & 1, wr = w >> 1;
    int ml = lane & 31, kh = lane >> 5;
    int oc0 = ocq * 64 + wo * 32;

    floatx16 acc[4];
    #pragma unroll
    for (int j = 0; j < 4; ++j)
        #pragma unroll
        for (int r = 0; r < 16; ++r) acc[j][r] = 0.f;

    const unsigned short* xtb = x_t + (size_t)b * HW_ * CIN_;
    const unsigned short* aln = agg + (((size_t)b * 9 * COUT_) + oc0 + ml) * CIN_ + kh * 8;

    // rolling A prefetch: taps rs = dy*3+dx for current dx
    short8 Acur0, Acur1, Acur2, Anext0, Anext1, Anext2;
    Acur0 = *(const short8*)(aln + (size_t)0 * (COUT_ * CIN_));
    Acur1 = *(const short8*)(aln + (size_t)3 * (COUT_ * CIN_));
    Acur2 = *(const short8*)(aln + (size_t)6 * (COUT_ * CIN_));
    int dxn = 1, kkn = 0, icn = 0;

    for (int c = 0; c < 4; ++c) {
        if (c) __syncthreads();   // readers of previous chunk done
        // stage Xs: rows py0-1..py0+7, cols -1..33, ic chunk c
        #pragma unroll
        for (int i = 0; i < 10; ++i) {
            int l = t + i * 256;
            if (l < 2520) {
                int pos = l >> 3, g = l & 7;
                int row = pos / 35, col = pos - row * 35;
                int gy = py0 - 1 + row, gx = col - 1;
                short8 v = (short8)0;
                if ((unsigned)gy < 28u && (unsigned)gx < 28u)
                    v = *(const short8*)(xtb + ((size_t)(gy * W_ + gx)) * CIN_ + c * 64 + g * 8);
                *(short8*)&Xs[pos * 72 + g * 8] = v;
            }
        }
        __syncthreads();

        for (int kk = 0; kk < 4; ++kk) {
            for (int dx = 0; dx < 3; ++dx) {
                if (icn < 256) {
                    const unsigned short* ap = aln + icn + kkn * 16;
                    Anext0 = *(const short8*)(ap + (size_t)(0 * 3 + dxn) * (COUT_ * CIN_));
                    Anext1 = *(const short8*)(ap + (size_t)(1 * 3 + dxn) * (COUT_ * CIN_));
                    Anext2 = *(const short8*)(ap + (size_t)(2 * 3 + dxn) * (COUT_ * CIN_));
                    ++dxn;
                    if (dxn == 3) { dxn = 0; ++kkn; if (kkn == 4) { kkn = 0; icn += 64; } }
                }
                int va = (ml + dx) * 72 + kk * 16 + kh * 8;
                if (wr == 0) {
                    // output rows 0..3; B rows 0..5
                    #pragma unroll
                    for (int r = 0; r < 6; ++r) {
                        short8 Bf = *(const short8*)&Xs[r * 2520 + va];
                        if (r <= 3)
                            acc[r]     = __builtin_amdgcn_mfma_f32_32x32x16_bf16(Acur0, Bf, acc[r], 0, 0, 0);
                        if (r >= 1 && r <= 4)
                            acc[r - 1] = __builtin_amdgcn_mfma_f32_32x32x16_bf16(Acur1, Bf, acc[r - 1], 0, 0, 0);
                        if (r >= 2)
                            acc[r - 2] = __builtin_amdgcn_mfma_f32_32x32x16_bf16(Acur2, Bf, acc[r - 2], 0, 0, 0);
                    }
                } else {
                    // output rows 4..6 (acc[0..2]); B rows 4..8
                    #pragma unroll
                    for (int rr2 = 0; rr2 < 5; ++rr2) {
                        int r = rr2 + 4;                  // 4..8
                        short8 Bf = *(const short8*)&Xs[r * 2520 + va];
                        int j0 = r - 4;                   // candidate acc for dy=0
                        if (j0 <= 2)
                            acc[j0]     = __builtin_amdgcn_mfma_f32_32x32x16_bf16(Acur0, Bf, acc[j0], 0, 0, 0);
                        if (r >= 5 && r - 5 <= 2)
                            acc[r - 5]  = __builtin_amdgcn_mfma_f32_32x32x16_bf16(Acur1, Bf, acc[r - 5], 0, 0, 0);
                        if (r >= 6)
                            acc[r - 6]  = __builtin_amdgcn_mfma_f32_32x32x16_bf16(Acur2, Bf, acc[r - 6], 0, 0, 0);
                    }
                }
                Acur0 = Anext0; Acur1 = Anext1; Acur2 = Anext2;
            }
        }
    }

    // epilogue: D layout col=lane&31, row=(reg&3)+8*(reg>>2)+4*(lane>>5)
    int jbase = wr * 4;
    int naccs = wr ? 3 : 4;
    if (ml < W_) {
        for (int j = 0; j < naccs; ++j) {
            float* op = out + ((size_t)(b * COUT_ + oc0)) * HW_ + (py0 + jbase + j) * W_ + ml;
            #pragma unroll
            for (int r = 0; r < 16; ++r) {
                int ocd = (r & 3) + 8 * (r >> 2) + 4 * kh;
                op[(size_t)ocd * HW_] = acc[j][r];
            }
        }
    }
}

// ---------------- Fallback path (ws too small): fp32 direct ----------------
__global__ __launch_bounds__(256) void pool_kernel(const float* __restrict__ x,
                                                   float* __restrict__ pooled) {
    int w = blockIdx.x * 4 + (threadIdx.x >> 6);
    int lane = threadIdx.x & 63;
    const float* p = x + (size_t)w * HW_;
    float s = 0.f;
    for (int i = lane; i < HW_; i += 64) s += p[i];
    for (int off = 32; off; off >>= 1) s += __shfl_down(s, off);
    if (lane == 0) pooled[w] = s * (1.0f / HW_);
}

__global__ __launch_bounds__(256) void se2_kernel(const float* __restrict__ pooled,
                                                  const float* __restrict__ fc1_w,
                                                  const float* __restrict__ fc2_w,
                                                  const float* __restrict__ fc2_b,
                                                  float* __restrict__ prob) {
    __shared__ float pl[CIN_];
    __shared__ float h[HID_];
    __shared__ float wb[16640];
    int b = blockIdx.x, t = threadIdx.x;
    pl[t] = pooled[b * CIN_ + t];
    #pragma unroll
    for (int i = 0; i < 16; ++i) {
        int l = t + i * 256;
        float4 v = *(const float4*)(fc1_w + (size_t)l * 4);
        int r = l >> 6, cc = (l & 63) * 4;
        float* dst = &wb[r * 257 + cc];
        dst[0] = v.x; dst[1] = v.y; dst[2] = v.z; dst[3] = v.w;
    }
    __syncthreads();
    if (t < HID_) {
        float s = 0.f;
        const float* wr = &wb[t * 257];
        for (int c = 0; c < CIN_; ++c) s += pl[c] * wr[c];
        h[t] = fmaxf(s, 0.f);
    }
    float yk[KEXP_];
    for (int k = 0; k < KEXP_; ++k) {
        __syncthreads();
        #pragma unroll
        for (int i = 0; i < 16; ++i) {
            int l = t + i * 256;
            float4 v = *(const float4*)(fc2_w + (size_t)k * COUT_ * HID_ + (size_t)l * 4);
            int o = l >> 4, jj = (l & 15) * 4;
            float* dst = &wb[o * 65 + jj];
            dst[0] = v.x; dst[1] = v.y; dst[2] = v.z; dst[3] = v.w;
        }
        __syncthreads();
        float s = fc2_b[k * COUT_ + t];
        const float* wr = &wb[t * 65];
        #pragma unroll
        for (int j = 0; j < HID_; ++j) s += h[j] * wr[j];
        yk[k] = s * 0.125f;
    }
    float m = yk[0];
    for (int k = 1; k < KEXP_; ++k) m = fmaxf(m, yk[k]);
    float e[KEXP_], sum = 0.f;
    for (int k = 0; k < KEXP_; ++k) { e[k] = expf(yk[k] - m); sum += e[k]; }
    float inv = 1.0f / sum;
    for (int k = 0; k < KEXP_; ++k)
        prob[b * (KEXP_ * COUT_) + k * COUT_ + t] = e[k] * inv;
}

__global__ __launch_bounds__(256) void conv_kernel(const float* __restrict__ x,
                                                   const float* __restrict__ weight,
                                                   const float* __restrict__ prob,
                                                   float* __restrict__ out) {
    __shared__ float xs[30 * 30];
    __shared__ float wagg[8][32][12];
    __shared__ float pl[KEXP_][8];

    int b  = blockIdx.x >> 5;
    int o0 = (blockIdx.x & 31) * 8;
    int t  = threadIdx.x;

    if (t < 32) {
        int k = t >> 3, oc = t & 7;
        pl[k][oc] = prob[b * (KEXP_ * COUT_) + k * COUT_ + o0 + oc];
    }
    int p0 = t;
    int pr[4], pc[4];
    bool pv[4];
    #pragma unroll
    for (int j = 0; j < 4; ++j) {
        int p = p0 + j * 256;
        pv[j] = p < HW_;
        pr[j] = p / W_;
        pc[j] = p % W_;
    }
    float acc[8][4];
    #pragma unroll
    for (int oc = 0; oc < 8; ++oc)
        #pragma unroll
        for (int j = 0; j < 4; ++j) acc[oc][j] = 0.f;

    int aoc = t >> 5, aii = t & 31;

    for (int ic0 = 0; ic0 < CIN_; ic0 += 32) {
        __syncthreads();
        {
            float w9[9];
            #pragma unroll
            for (int j = 0; j < 9; ++j) w9[j] = 0.f;
            int i = ic0 + aii;
            #pragma unroll
            for (int k = 0; k < KEXP_; ++k) {
                float pk = pl[k][aoc];
                const float* wp = weight + ((size_t)(k * COUT_ + o0 + aoc) * CIN_ + i) * 9;
                #pragma unroll
                for (int j = 0; j < 9; ++j) w9[j] += pk * wp[j];
            }
            #pragma unroll
            for (int j = 0; j < 9; ++j) wagg[aoc][aii][j] = w9[j];
        }
        for (int ii = 0; ii < 32; ++ii) {
            int i = ic0 + ii;
            __syncthreads();
            const float* xp = x + (size_t)(b * CIN_ + i) * HW_;
            for (int e = t; e < 900; e += 256) {
                int ry = e / 30, cx = e - ry * 30;
                int gy = ry - 1, gx = cx - 1;
                float v = 0.f;
                if ((unsigned)gy < 28u && (unsigned)gx < 28u) v = xp[gy * W_ + gx];
                xs[e] = v;
            }
            __syncthreads();
            float xv[4][9];
            #pragma unroll
            for (int j = 0; j < 4; ++j) {
                if (pv[j]) {
                    const float* xr = &xs[pr[j] * 30 + pc[j]];
                    xv[j][0] = xr[0];  xv[j][1] = xr[1];  xv[j][2] = xr[2];
                    xv[j][3] = xr[30]; xv[j][4] = xr[31]; xv[j][5] = xr[32];
                    xv[j][6] = xr[60]; xv[j][7] = xr[61]; xv[j][8] = xr[62];
                } else {
                    #pragma unroll
                    for (int q = 0; q < 9; ++q) xv[j][q] = 0.f;
                }
            }
            #pragma unroll
            for (int oc = 0; oc < 8; ++oc) {
                float4 wa = *(const float4*)&wagg[oc][ii][0];
                float4 wb2 = *(const float4*)&wagg[oc][ii][4];
                float  wc = wagg[oc][ii][8];
                #pragma unroll
                for (int j = 0; j < 4; ++j) {
                    acc[oc][j] += xv[j][0] * wa.x + xv[j][1] * wa.y + xv[j][2] * wa.z
                                + xv[j][3] * wa.w + xv[j][4] * wb2.x + xv[j][5] * wb2.y
                                + xv[j][6] * wb2.z + xv[j][7] * wb2.w + xv[j][8] * wc;
                }
            }
        }
    }
    #pragma unroll
    for (int oc = 0; oc < 8; ++oc) {
        float* op = out + (size_t)(b * COUT_ + o0 + oc) * HW_ + p0;
        #pragma unroll
        for (int j = 0; j < 4; ++j)
            if (pv[j]) op[j * 256] = acc[oc][j];
    }
}

extern "C" void kernel_launch(void* const* d_in, const int* in_sizes, int n_in,
                              void* d_out, int out_size, void* d_ws, size_t ws_size,
                              hipStream_t stream) {
    const float* x     = (const float*)d_in[0];
    const float* fc1_w = (const float*)d_in[1];
    const float* fc2_w = (const float*)d_in[2];
    const float* fc2_b = (const float*)d_in[3];
    const float* weight= (const float*)d_in[4];
    float* out = (float*)d_out;

    char* ws = (char*)d_ws;
    float* h_g  = (float*)(ws);                                   // 8 KB (main) / prob (fallback)
    unsigned short* x_t = (unsigned short*)(ws + 131072);         // 12,845,056 B
    unsigned short* agg = (unsigned short*)(ws + 12976128);       // 37,748,736 B
    float* partial = (float*)(ws + 12976128);                     // 819,200 B (overlaps agg; read before agg writes)
    const size_t WS_NEED = 12976128 + (size_t)B_ * 9 * COUT_ * CIN_ * 2;  // 50,724,864

    if (ws_size >= WS_NEED) {
        xpose_pool_kernel<<<B_ * 8 * 25, 256, 0, stream>>>(x, x_t, partial);
        se_h_kernel<<<B_, 256, 0, stream>>>(partial, fc1_w, h_g);
        agg5_kernel<<<512, 256, 0, stream>>>(weight, h_g, fc2_w, fc2_b, agg);
        conv_mfma5_kernel<<<512, 256, 0, stream>>>(x_t, agg, out);
    } else {
        float* prob = (float*)(ws);
        float* pooled = (float*)(ws + 131072);
        pool_kernel<<<(B_ * CIN_) / 4, 256, 0, stream>>>(x, pooled);
        se2_kernel<<<B_, 256, 0, stream>>>(pooled, fc1_w, fc2_w, fc2_b, prob);
        conv_kernel<<<B_ * (COUT_ / 8), 256, 0, stream>>>(x, weight, prob, out);
    }
}

// Round 8
// 262.413 us; speedup vs baseline: 1.0113x; 1.0113x over previous
//
#include <hip/hip_runtime.h>
#include <math.h>

#define B_    32
#define CIN_  256
#define HW_   784
#define H_    28
#define W_    28
#define COUT_ 256
#define KEXP_ 4
#define HID_  64

typedef short short8 __attribute__((ext_vector_type(8)));
typedef float floatx16 __attribute__((ext_vector_type(16)));

__device__ __forceinline__ unsigned short f2bf(float f) {
    union { float f; unsigned int u; } v; v.f = f;
    unsigned int r = (v.u + 0x7FFFu + ((v.u >> 16) & 1u)) >> 16;
    return (unsigned short)r;
}

// ---------------- Kernel 1: transpose + partial pool ----------------
__global__ __launch_bounds__(256) void xpose_pool_kernel(const float* __restrict__ x,
                                                         unsigned short* __restrict__ x_t,
                                                         float* __restrict__ partial) {
    __shared__ float tile[32][33];
    int bid = blockIdx.x;              // 32 * 8 * 25
    int b   = bid / 200;
    int rem = bid - b * 200;
    int icg = rem / 25;
    int pxt = rem % 25;
    int ic0 = icg * 32;
    int px0 = pxt * 32;
    int t = threadIdx.x;
    int c = t & 31, rr = t >> 5;
    #pragma unroll
    for (int r = 0; r < 4; ++r) {
        int icr = rr + r * 8;
        int px = px0 + c;
        float v = (px < HW_) ? x[((size_t)(b * CIN_ + ic0 + icr)) * HW_ + px] : 0.f;
        tile[icr][c] = v;
    }
    __syncthreads();
    #pragma unroll
    for (int r = 0; r < 4; ++r) {
        int pxr = rr + r * 8;
        int px = px0 + pxr;
        if (px < HW_)
            x_t[((size_t)b * HW_ + px) * CIN_ + ic0 + c] = f2bf(tile[c][pxr]);
    }
    if (t < 32) {
        float s = 0.f;
        #pragma unroll
        for (int cc = 0; cc < 32; ++cc) s += tile[t][cc];
        partial[((size_t)b * 25 + pxt) * CIN_ + ic0 + t] = s * (1.0f / HW_);
    }
}

// ---------------- Kernel 2: fused pool-reduce + fc1 + fc2 + softmax + aggregate ----------------
// grid = 256: b = bid&31, ocg = bid>>5 (group of 32 oc)
// agg packed layout: region r = ((b*9+rs)*16 + ickk)*8 + ocg ; shorts: r*512 + lane*8
//   lane = kh*32 + (oc&31), covers ic = ickk*16 + kh*8 + 0..7
__global__ __launch_bounds__(256) void agg6_kernel(const float* __restrict__ weight,
                                                   const float* __restrict__ partial,
                                                   const float* __restrict__ fc1_w,
                                                   const float* __restrict__ fc2_w,
                                                   const float* __restrict__ fc2_b,
                                                   unsigned short* __restrict__ agg) {
    __shared__ float pl[CIN_];
    __shared__ float h[HID_];
    __shared__ float pb[KEXP_][32];
    int bid = blockIdx.x;
    int b = bid & 31, ocg = bid >> 5;
    int t = threadIdx.x;

    // pool-reduce
    {
        float s = 0.f;
        for (int pt = 0; pt < 25; ++pt)
            s += partial[((size_t)b * 25 + pt) * CIN_ + t];
        pl[t] = s;
    }
    __syncthreads();
    // fc1: 4 threads per hidden unit
    {
        int hi = t >> 2, q = t & 3;
        const float* wr = fc1_w + (size_t)hi * CIN_ + q * 64;
        const float* pr = &pl[q * 64];
        float a = 0.f;
        #pragma unroll
        for (int j = 0; j < 64; ++j) a += pr[j] * wr[j];
        a += __shfl_xor(a, 1);
        a += __shfl_xor(a, 2);
        if (q == 0) h[hi] = fmaxf(a, 0.f);
    }
    __syncthreads();
    // fc2 + softmax over K (4 lanes per oc: k = t&3)
    if (t < 128) {
        int ol = t >> 2, k = t & 3;
        int oc = ocg * 32 + ol;
        const float* fr = fc2_w + ((size_t)(k * COUT_ + oc)) * HID_;
        float y = fc2_b[k * COUT_ + oc];
        #pragma unroll
        for (int j = 0; j < HID_; ++j) y += h[j] * fr[j];
        y *= 0.125f;
        float m = fmaxf(y, __shfl_xor(y, 1));
        m = fmaxf(m, __shfl_xor(m, 2));
        float e = expf(y - m);
        float s1 = e + __shfl_xor(e, 1);
        float s2 = s1 + __shfl_xor(s1, 2);
        pb[k][ol] = e / s2;
    }
    __syncthreads();

    // aggregate: thread covers (oc = ocg*32 + (t&31), ic-groups g = (t>>5) + 8p)
    int oc_l = t & 31, gg = t >> 5;
    int oc = ocg * 32 + oc_l;
    float p0 = pb[0][oc_l], p1 = pb[1][oc_l], p2 = pb[2][oc_l], p3 = pb[3][oc_l];
    const float* w0 = weight + (size_t)0 * 589824 + (size_t)oc * 2304;
    const float* w1 = weight + (size_t)1 * 589824 + (size_t)oc * 2304;
    const float* w2 = weight + (size_t)2 * 589824 + (size_t)oc * 2304;
    const float* w3 = weight + (size_t)3 * 589824 + (size_t)oc * 2304;
    #pragma unroll
    for (int p = 0; p < 4; ++p) {
        int g = p * 8 + gg;            // 0..31, ic0 = g*8
        int ic0 = g * 8;
        for (int rs = 0; rs < 9; ++rs) {
            unsigned short vals[8];
            #pragma unroll
            for (int j = 0; j < 8; ++j) {
                int wi = (ic0 + j) * 9 + rs;
                float s = p0 * w0[wi] + p1 * w1[wi] + p2 * w2[wi] + p3 * w3[wi];
                vals[j] = f2bf(s);
            }
            size_t region = ((size_t)(b * 9 + rs) * 16 + (g >> 1)) * 8 + ocg;
            *(short8*)(agg + region * 512 + ((g & 1) * 32 + oc_l) * 8) = *(short8*)vals;
        }
    }
}

// ---------------- Kernel 3: MFMA conv, packed-A contiguous loads ----------------
// grid = 256: b = gid&31, half = (gid>>5)&1, rowblk = gid>>6 (7 rows each)
__global__ __launch_bounds__(256, 1) void conv_mfma6_kernel(const unsigned short* __restrict__ x_t,
                                                            const unsigned short* __restrict__ agg,
                                                            float* __restrict__ out) {
    __shared__ __align__(16) short Xs[2][9 * 35 * 72];   // 2 x 45360 B

    int gid = blockIdx.x;
    int b      = gid & 31;
    int half   = (gid >> 5) & 1;
    int rowblk = gid >> 6;
    int py0 = rowblk * 7;

    int t = threadIdx.x;
    int lane = t & 63, w = t >> 6;
    int ml = lane & 31, kh = lane >> 5;
    int oc0 = half * 128 + w * 32;
    int ocg_w = half * 4 + w;

    floatx16 acc[7];
    #pragma unroll
    for (int j = 0; j < 7; ++j)
        #pragma unroll
        for (int r = 0; r < 16; ++r) acc[j][r] = 0.f;

    const unsigned short* xtb = x_t + (size_t)b * HW_ * CIN_;
    // packed A: offset shorts = ((b*9+rs)*16 + ik)*8 + ocg_w)*512 + lane*8
    const unsigned short* aln = agg + ((size_t)(b * 9 * 16 * 8 + ocg_w)) * 512 + lane * 8;
    // tap stride: rs -> +16*8*512 = 65536 shorts ; ik -> +8*512 = 4096 shorts

    // ---- stage chunk 0 into buf 0 ----
    #pragma unroll
    for (int i = 0; i < 10; ++i) {
        int l = t + i * 256;
        if (l < 2520) {
            int pos = l >> 3, g = l & 7;
            int row = pos / 35, col = pos - row * 35;
            int gy = py0 - 1 + row, gx = col - 1;
            short8 v = (short8)0;
            if ((unsigned)gy < 28u && (unsigned)gx < 28u)
                v = *(const short8*)(xtb + ((size_t)(gy * W_ + gx)) * CIN_ + g * 8);
            *(short8*)&Xs[0][pos * 72 + g * 8] = v;
        }
    }

    // prologue A: taps rs=0,3,6 at ik=0
    short8 Acur0, Acur1, Acur2, Anext0, Anext1, Anext2;
    Acur0 = *(const short8*)(aln + (size_t)0 * 65536);
    Acur1 = *(const short8*)(aln + (size_t)3 * 65536);
    Acur2 = *(const short8*)(aln + (size_t)6 * 65536);
    int dxn = 1, kkn = 0, icn = 0;

    __syncthreads();

    for (int c = 0; c < 4; ++c) {
        const short* xb = &Xs[c & 1][0];

        short8 Xl[10];
        if (c < 3) {
            #pragma unroll
            for (int i = 0; i < 10; ++i) {
                int l = t + i * 256;
                short8 v = (short8)0;
                if (l < 2520) {
                    int pos = l >> 3, g = l & 7;
                    int row = pos / 35, col = pos - row * 35;
                    int gy = py0 - 1 + row, gx = col - 1;
                    if ((unsigned)gy < 28u && (unsigned)gx < 28u)
                        v = *(const short8*)(xtb + ((size_t)(gy * W_ + gx)) * CIN_ + c * 64 + 64 + g * 8);
                }
                Xl[i] = v;
            }
        }

        for (int kk = 0; kk < 4; ++kk) {
            for (int dx = 0; dx < 3; ++dx) {
                // rolling A prefetch: next (icn,kkn,dxn) triple of taps
                if (icn < 256) {
                    size_t iko = (size_t)((icn >> 4) + kkn) * 4096;
                    Anext0 = *(const short8*)(aln + (size_t)(0 + dxn) * 65536 + iko);
                    Anext1 = *(const short8*)(aln + (size_t)(3 + dxn) * 65536 + iko);
                    Anext2 = *(const short8*)(aln + (size_t)(6 + dxn) * 65536 + iko);
                    ++dxn;
                    if (dxn == 3) { dxn = 0; ++kkn; if (kkn == 4) { kkn = 0; icn += 64; } }
                }
                int va = (ml + dx) * 72 + kk * 16 + kh * 8;
                #pragma unroll
                for (int r = 0; r < 9; ++r) {
                    short8 Bf = *(const short8*)&xb[r * 2520 + va];
                    if (r <= 6)
                        acc[r]     = __builtin_amdgcn_mfma_f32_32x32x16_bf16(Acur0, Bf, acc[r], 0, 0, 0);
                    if (r >= 1 && r - 1 <= 6)
                        acc[r - 1] = __builtin_amdgcn_mfma_f32_32x32x16_bf16(Acur1, Bf, acc[r - 1], 0, 0, 0);
                    if (r >= 2)
                        acc[r - 2] = __builtin_amdgcn_mfma_f32_32x32x16_bf16(Acur2, Bf, acc[r - 2], 0, 0, 0);
                }
                Acur0 = Anext0; Acur1 = Anext1; Acur2 = Anext2;
            }
        }

        if (c < 3) {
            short* dstb = &Xs[(c & 1) ^ 1][0];
            #pragma unroll
            for (int i = 0; i < 10; ++i) {
                int l = t + i * 256;
                if (l < 2520) {
                    int pos = l >> 3, g = l & 7;
                    *(short8*)&dstb[pos * 72 + g * 8] = Xl[i];
                }
            }
        }
        __syncthreads();
    }

    // epilogue: D layout col=lane&31, row=(reg&3)+8*(reg>>2)+4*(lane>>5)
    if (ml < W_) {
        #pragma unroll
        for (int j = 0; j < 7; ++j) {
            float* op = out + ((size_t)(b * COUT_ + oc0)) * HW_ + (py0 + j) * W_ + ml;
            #pragma unroll
            for (int r = 0; r < 16; ++r) {
                int ocd = (r & 3) + 8 * (r >> 2) + 4 * kh;
                op[(size_t)ocd * HW_] = acc[j][r];
            }
        }
    }
}

// ---------------- Fallback path (ws too small): fp32 direct ----------------
__global__ __launch_bounds__(256) void pool_kernel(const float* __restrict__ x,
                                                   float* __restrict__ pooled) {
    int w = blockIdx.x * 4 + (threadIdx.x >> 6);
    int lane = threadIdx.x & 63;
    const float* p = x + (size_t)w * HW_;
    float s = 0.f;
    for (int i = lane; i < HW_; i += 64) s += p[i];
    for (int off = 32; off; off >>= 1) s += __shfl_down(s, off);
    if (lane == 0) pooled[w] = s * (1.0f / HW_);
}

__global__ __launch_bounds__(256) void se2_kernel(const float* __restrict__ pooled,
                                                  const float* __restrict__ fc1_w,
                                                  const float* __restrict__ fc2_w,
                                                  const float* __restrict__ fc2_b,
                                                  float* __restrict__ prob) {
    __shared__ float pl[CIN_];
    __shared__ float h[HID_];
    __shared__ float wb[16640];
    int b = blockIdx.x, t = threadIdx.x;
    pl[t] = pooled[b * CIN_ + t];
    #pragma unroll
    for (int i = 0; i < 16; ++i) {
        int l = t + i * 256;
        float4 v = *(const float4*)(fc1_w + (size_t)l * 4);
        int r = l >> 6, cc = (l & 63) * 4;
        float* dst = &wb[r * 257 + cc];
        dst[0] = v.x; dst[1] = v.y; dst[2] = v.z; dst[3] = v.w;
    }
    __syncthreads();
    if (t < HID_) {
        float s = 0.f;
        const float* wr = &wb[t * 257];
        for (int c = 0; c < CIN_; ++c) s += pl[c] * wr[c];
        h[t] = fmaxf(s, 0.f);
    }
    float yk[KEXP_];
    for (int k = 0; k < KEXP_; ++k) {
        __syncthreads();
        #pragma unroll
        for (int i = 0; i < 16; ++i) {
            int l = t + i * 256;
            float4 v = *(const float4*)(fc2_w + (size_t)k * COUT_ * HID_ + (size_t)l * 4);
            int o = l >> 4, jj = (l & 15) * 4;
            float* dst = &wb[o * 65 + jj];
            dst[0] = v.x; dst[1] = v.y; dst[2] = v.z; dst[3] = v.w;
        }
        __syncthreads();
        float s = fc2_b[k * COUT_ + t];
        const float* wr = &wb[t * 65];
        #pragma unroll
        for (int j = 0; j < HID_; ++j) s += h[j] * wr[j];
        yk[k] = s * 0.125f;
    }
    float m = yk[0];
    for (int k = 1; k < KEXP_; ++k) m = fmaxf(m, yk[k]);
    float e[KEXP_], sum = 0.f;
    for (int k = 0; k < KEXP_; ++k) { e[k] = expf(yk[k] - m); sum += e[k]; }
    float inv = 1.0f / sum;
    for (int k = 0; k < KEXP_; ++k)
        prob[b * (KEXP_ * COUT_) + k * COUT_ + t] = e[k] * inv;
}

__global__ __launch_bounds__(256) void conv_kernel(const float* __restrict__ x,
                                                   const float* __restrict__ weight,
                                                   const float* __restrict__ prob,
                                                   float* __restrict__ out) {
    __shared__ float xs[30 * 30];
    __shared__ float wagg[8][32][12];
    __shared__ float pl[KEXP_][8];

    int b  = blockIdx.x >> 5;
    int o0 = (blockIdx.x & 31) * 8;
    int t  = threadIdx.x;

    if (t < 32) {
        int k = t >> 3, oc = t & 7;
        pl[k][oc] = prob[b * (KEXP_ * COUT_) + k * COUT_ + o0 + oc];
    }
    int p0 = t;
    int pr[4], pc[4];
    bool pv[4];
    #pragma unroll
    for (int j = 0; j < 4; ++j) {
        int p = p0 + j * 256;
        pv[j] = p < HW_;
        pr[j] = p / W_;
        pc[j] = p % W_;
    }
    float acc[8][4];
    #pragma unroll
    for (int oc = 0; oc < 8; ++oc)
        #pragma unroll
        for (int j = 0; j < 4; ++j) acc[oc][j] = 0.f;

    int aoc = t >> 5, aii = t & 31;

    for (int ic0 = 0; ic0 < CIN_; ic0 += 32) {
        __syncthreads();
        {
            float w9[9];
            #pragma unroll
            for (int j = 0; j < 9; ++j) w9[j] = 0.f;
            int i = ic0 + aii;
            #pragma unroll
            for (int k = 0; k < KEXP_; ++k) {
                float pk = pl[k][aoc];
                const float* wp = weight + ((size_t)(k * COUT_ + o0 + aoc) * CIN_ + i) * 9;
                #pragma unroll
                for (int j = 0; j < 9; ++j) w9[j] += pk * wp[j];
            }
            #pragma unroll
            for (int j = 0; j < 9; ++j) wagg[aoc][aii][j] = w9[j];
        }
        for (int ii = 0; ii < 32; ++ii) {
            int i = ic0 + ii;
            __syncthreads();
            const float* xp = x + (size_t)(b * CIN_ + i) * HW_;
            for (int e = t; e < 900; e += 256) {
                int ry = e / 30, cx = e - ry * 30;
                int gy = ry - 1, gx = cx - 1;
                float v = 0.f;
                if ((unsigned)gy < 28u && (unsigned)gx < 28u) v = xp[gy * W_ + gx];
                xs[e] = v;
            }
            __syncthreads();
            float xv[4][9];
            #pragma unroll
            for (int j = 0; j < 4; ++j) {
                if (pv[j]) {
                    const float* xr = &xs[pr[j] * 30 + pc[j]];
                    xv[j][0] = xr[0];  xv[j][1] = xr[1];  xv[j][2] = xr[2];
                    xv[j][3] = xr[30]; xv[j][4] = xr[31]; xv[j][5] = xr[32];
                    xv[j][6] = xr[60]; xv[j][7] = xr[61]; xv[j][8] = xr[62];
                } else {
                    #pragma unroll
                    for (int q = 0; q < 9; ++q) xv[j][q] = 0.f;
                }
            }
            #pragma unroll
            for (int oc = 0; oc < 8; ++oc) {
                float4 wa = *(const float4*)&wagg[oc][ii][0];
                float4 wb2 = *(const float4*)&wagg[oc][ii][4];
                float  wc = wagg[oc][ii][8];
                #pragma unroll
                for (int j = 0; j < 4; ++j) {
                    acc[oc][j] += xv[j][0] * wa.x + xv[j][1] * wa.y + xv[j][2] * wa.z
                                + xv[j][3] * wa.w + xv[j][4] * wb2.x + xv[j][5] * wb2.y
                                + xv[j][6] * wb2.z + xv[j][7] * wb2.w + xv[j][8] * wc;
                }
            }
        }
    }
    #pragma unroll
    for (int oc = 0; oc < 8; ++oc) {
        float* op = out + (size_t)(b * COUT_ + o0 + oc) * HW_ + p0;
        #pragma unroll
        for (int j = 0; j < 4; ++j)
            if (pv[j]) op[j * 256] = acc[oc][j];
    }
}

extern "C" void kernel_launch(void* const* d_in, const int* in_sizes, int n_in,
                              void* d_out, int out_size, void* d_ws, size_t ws_size,
                              hipStream_t stream) {
    const float* x     = (const float*)d_in[0];
    const float* fc1_w = (const float*)d_in[1];
    const float* fc2_w = (const float*)d_in[2];
    const float* fc2_b = (const float*)d_in[3];
    const float* weight= (const float*)d_in[4];
    float* out = (float*)d_out;

    char* ws = (char*)d_ws;
    // layout: partial @0 (819200), x_t @851968 (12845056), agg @13697024 (37748736)
    float* partial = (float*)(ws);
    unsigned short* x_t = (unsigned short*)(ws + 851968);
    unsigned short* agg = (unsigned short*)(ws + 13697024);
    const size_t WS_NEED = 13697024 + 37748736;   // 51,445,760

    if (ws_size >= WS_NEED) {
        xpose_pool_kernel<<<B_ * 8 * 25, 256, 0, stream>>>(x, x_t, partial);
        agg6_kernel<<<256, 256, 0, stream>>>(weight, partial, fc1_w, fc2_w, fc2_b, agg);
        conv_mfma6_kernel<<<256, 256, 0, stream>>>(x_t, agg, out);
    } else {
        float* prob = (float*)(ws);
        float* pooled = (float*)(ws + 131072);
        pool_kernel<<<(B_ * CIN_) / 4, 256, 0, stream>>>(x, pooled);
        se2_kernel<<<B_, 256, 0, stream>>>(pooled, fc1_w, fc2_w, fc2_b, prob);
        conv_kernel<<<B_ * (COUT_ / 8), 256, 0, stream>>>(x, weight, prob, out);
    }
}

// Round 9
// 172.453 us; speedup vs baseline: 1.5389x; 1.5216x over previous
//
#include <hip/hip_runtime.h>
#include <math.h>

#define B_    32
#define CIN_  256
#define HW_   784
#define H_    28
#define W_    28
#define COUT_ 256
#define KEXP_ 4
#define HID_  64

typedef short short8 __attribute__((ext_vector_type(8)));
typedef unsigned short ushort4v __attribute__((ext_vector_type(4)));
typedef float floatx16 __attribute__((ext_vector_type(16)));

__device__ __forceinline__ unsigned short f2bf(float f) {
    union { float f; unsigned int u; } v; v.f = f;
    unsigned int r = (v.u + 0x7FFFu + ((v.u >> 16) & 1u)) >> 16;
    return (unsigned short)r;
}

// ---------------- Kernel 1: transpose + partial pool (full-line bf16 writes) ----------------
// grid = 32b * 4icg * 25pxt = 3200 ; tile = 64 ic x 32 px
// block 0 additionally writes fc1T[c][hi] (transposed fc1 weights)
__global__ __launch_bounds__(256) void xpose2_kernel(const float* __restrict__ x,
                                                     const float* __restrict__ fc1_w,
                                                     unsigned short* __restrict__ x_t,
                                                     float* __restrict__ partial,
                                                     float* __restrict__ fc1T) {
    __shared__ float tile[64][33];
    int bid = blockIdx.x;
    int b   = bid / 100;
    int rem = bid - b * 100;
    int icg = rem / 25;
    int pxt = rem % 25;
    int ic0 = icg * 64;
    int px0 = pxt * 32;
    int t = threadIdx.x;
    int pxl = t & 31, icr0 = t >> 5;
    #pragma unroll
    for (int r = 0; r < 8; ++r) {
        int icr = icr0 + r * 8;
        int px = px0 + pxl;
        float v = (px < HW_) ? x[((size_t)(b * CIN_ + ic0 + icr)) * HW_ + px] : 0.f;
        tile[icr][pxl] = v;
    }
    __syncthreads();
    // partial pool: 64 threads, one per ic
    if (t < 64) {
        float s = 0.f;
        #pragma unroll
        for (int cc = 0; cc < 32; ++cc) s += tile[t][cc];
        partial[((size_t)b * 25 + pxt) * CIN_ + ic0 + t] = s * (1.0f / HW_);
    }
    // store: thread (pxl2 = t>>3, icq = t&7) writes short8 -> 8 lanes = 128B line
    {
        int pxl2 = t >> 3, icq = t & 7;
        int px = px0 + pxl2;
        if (px < HW_) {
            unsigned short vals[8];
            #pragma unroll
            for (int j = 0; j < 8; ++j) vals[j] = f2bf(tile[icq * 8 + j][pxl2]);
            *(short8*)(x_t + ((size_t)b * HW_ + px) * CIN_ + ic0 + icq * 8) = *(short8*)vals;
        }
    }
    // one block transposes fc1_w [64][256] -> fc1T [256][64]
    if (bid == 0) {
        #pragma unroll
        for (int i = 0; i < 16; ++i) {
            int l = t + i * 256;                 // float4 index over 16384 floats
            float4 v = *(const float4*)(fc1_w + (size_t)l * 4);
            int hi = l >> 6, c0 = (l & 63) * 4;
            fc1T[(size_t)(c0 + 0) * HID_ + hi] = v.x;
            fc1T[(size_t)(c0 + 1) * HID_ + hi] = v.y;
            fc1T[(size_t)(c0 + 2) * HID_ + hi] = v.z;
            fc1T[(size_t)(c0 + 3) * HID_ + hi] = v.w;
        }
    }
}

// ---------------- Kernel 2: fused SE (pool-reduce + fc1 + fc2 + softmax) + aggregate ----------------
// grid = 512: oc = bid&255, b0 = (bid>>8)*16 ; agg[b][rs][oc][ic] bf16
__global__ __launch_bounds__(256, 2) void agg8_kernel(const float* __restrict__ weight,
                                                      const float* __restrict__ partial,
                                                      const float* __restrict__ fc1T,
                                                      const float* __restrict__ fc2_w,
                                                      const float* __restrict__ fc2_b,
                                                      unsigned short* __restrict__ agg) {
    __shared__ float ws_w[KEXP_ * CIN_ * 9];   // [k][ic*9+rs] 36.9 KB
    __shared__ float pl[16 * 257];             // pooled per 16 samples
    __shared__ float hb[16 * 65];              // hidden
    __shared__ float pb[KEXP_ * 16];           // softmax probs
    int bid = blockIdx.x;
    int oc = bid & 255;
    int b0 = (bid >> 8) * 16;
    int t = threadIdx.x;

    // stage expert weights for this oc (independent of SE phases)
    #pragma unroll
    for (int i = 0; i < 9; ++i) {
        int e4 = t + i * 256;                  // 2304 float4s
        int k = e4 / 576;
        int r4 = e4 - k * 576;
        float4 v = *(const float4*)(weight + (size_t)k * 589824 + (size_t)oc * 2304 + (size_t)r4 * 4);
        *(float4*)&ws_w[e4 * 4] = v;
    }
    // phase 1: pool-reduce for 16 samples (coalesced, L2-hot)
    for (int bb = 0; bb < 16; ++bb) {
        float s = 0.f;
        for (int pt = 0; pt < 25; ++pt)
            s += partial[((size_t)(b0 + bb) * 25 + pt) * CIN_ + t];
        pl[bb * 257 + t] = s;
    }
    __syncthreads();
    // phase 2: fc1 — wave w handles samples w*4..w*4+3, lane = hidden unit
    {
        int w = t >> 6, lane = t & 63;
        float a0 = 0.f, a1 = 0.f, a2 = 0.f, a3 = 0.f;
        for (int c = 0; c < 256; ++c) {
            float wv = fc1T[(size_t)c * HID_ + lane];   // lane-contiguous, L2-hot
            a0 += pl[(w * 4 + 0) * 257 + c] * wv;       // LDS broadcast
            a1 += pl[(w * 4 + 1) * 257 + c] * wv;
            a2 += pl[(w * 4 + 2) * 257 + c] * wv;
            a3 += pl[(w * 4 + 3) * 257 + c] * wv;
        }
        hb[(w * 4 + 0) * 65 + lane] = fmaxf(a0, 0.f);
        hb[(w * 4 + 1) * 65 + lane] = fmaxf(a1, 0.f);
        hb[(w * 4 + 2) * 65 + lane] = fmaxf(a2, 0.f);
        hb[(w * 4 + 3) * 65 + lane] = fmaxf(a3, 0.f);
    }
    __syncthreads();
    // phase 3: fc2 + softmax over K (4 lanes per sample)
    if (t < 64) {
        int bb = t >> 2, k = t & 3;
        const float* fr = fc2_w + ((size_t)(k * COUT_ + oc)) * HID_;
        float y = fc2_b[k * COUT_ + oc];
        #pragma unroll
        for (int j = 0; j < HID_; ++j) y += hb[bb * 65 + j] * fr[j];
        y *= 0.125f;
        float m = fmaxf(y, __shfl_xor(y, 1));
        m = fmaxf(m, __shfl_xor(m, 2));
        float e = expf(y - m);
        float s1 = e + __shfl_xor(e, 1);
        float s2 = s1 + __shfl_xor(s1, 2);
        pb[k * 16 + bb] = e / s2;
    }
    __syncthreads();
    // phase 4: aggregation (agg4-proven body)
    int icg = t & 63, blane = t >> 6;
    for (int rs = 0; rs < 9; ++rs) {
        float wv[4][4];
        #pragma unroll
        for (int q = 0; q < 4; ++q)
            #pragma unroll
            for (int k = 0; k < 4; ++k)
                wv[q][k] = ws_w[k * 2304 + (icg * 4 + q) * 9 + rs];
        #pragma unroll
        for (int bb = 0; bb < 4; ++bb) {
            int bidx = blane * 4 + bb;
            float p0 = pb[0 * 16 + bidx], p1 = pb[1 * 16 + bidx];
            float p2 = pb[2 * 16 + bidx], p3 = pb[3 * 16 + bidx];
            ushort4v pack;
            #pragma unroll
            for (int q = 0; q < 4; ++q) {
                float s = p0 * wv[q][0] + p1 * wv[q][1] + p2 * wv[q][2] + p3 * wv[q][3];
                pack[q] = f2bf(s);
            }
            *(ushort4v*)(agg + (((size_t)(b0 + bidx) * 9 + rs) * COUT_ + oc) * CIN_ + icg * 4) = pack;
        }
    }
}

// ---------------- Kernel 3: MFMA conv, 4-row tiles, grid 512 = 2 blocks/CU balanced ----------------
// gid: b = gid&31, half = (gid>>5)&1, rowblk = gid>>6 (0..7), py0 = rowblk*4 (rows >=28 masked)
__global__ __launch_bounds__(256, 2) void conv7_kernel(const unsigned short* __restrict__ x_t,
                                                       const unsigned short* __restrict__ agg,
                                                       float* __restrict__ out) {
    __shared__ __align__(16) short Xs[6 * 35 * 72];   // 30240 B

    int gid = blockIdx.x;
    int b      = gid & 31;
    int oc0    = ((gid >> 5) & 1) * 128;
    int rowblk = gid >> 6;
    int py0 = rowblk * 4;

    int t = threadIdx.x;
    int lane = t & 63, w = t >> 6;
    int ml = lane & 31, kh = lane >> 5;

    floatx16 acc[4];
    #pragma unroll
    for (int j = 0; j < 4; ++j)
        #pragma unroll
        for (int r = 0; r < 16; ++r) acc[j][r] = 0.f;

    const unsigned short* xtb = x_t + (size_t)b * HW_ * CIN_;
    const unsigned short* aln = agg + (((size_t)b * 9 * COUT_) + oc0 + w * 32 + ml) * CIN_ + kh * 8;

    // prologue A: taps rs = 0,3,6 (dy=0,1,2 at dx=0), ic-chunk 0, kk 0
    short8 Acur0, Acur1, Acur2, Anext0, Anext1, Anext2;
    Acur0 = *(const short8*)(aln + (size_t)0 * (COUT_ * CIN_));
    Acur1 = *(const short8*)(aln + (size_t)3 * (COUT_ * CIN_));
    Acur2 = *(const short8*)(aln + (size_t)6 * (COUT_ * CIN_));
    int dxn = 1, kkn = 0, icn = 0;

    for (int c = 0; c < 4; ++c) {
        if (c) __syncthreads();
        // stage Xs: rows py0-1..py0+4, cols -1..33, ic chunk c
        #pragma unroll
        for (int i = 0; i < 7; ++i) {
            int l = t + i * 256;
            if (l < 1680) {
                int pos = l >> 3, g = l & 7;
                int row = pos / 35, col = pos - row * 35;
                int gy = py0 - 1 + row, gx = col - 1;
                short8 v = (short8)0;
                if ((unsigned)gy < 28u && (unsigned)gx < 28u)
                    v = *(const short8*)(xtb + ((size_t)(gy * W_ + gx)) * CIN_ + c * 64 + g * 8);
                *(short8*)&Xs[pos * 72 + g * 8] = v;
            }
        }
        __syncthreads();

        for (int kk = 0; kk < 4; ++kk) {
            for (int dx = 0; dx < 3; ++dx) {
                if (icn < 256) {
                    const unsigned short* ap = aln + icn + kkn * 16;
                    Anext0 = *(const short8*)(ap + (size_t)(0 * 3 + dxn) * (COUT_ * CIN_));
                    Anext1 = *(const short8*)(ap + (size_t)(1 * 3 + dxn) * (COUT_ * CIN_));
                    Anext2 = *(const short8*)(ap + (size_t)(2 * 3 + dxn) * (COUT_ * CIN_));
                    ++dxn;
                    if (dxn == 3) { dxn = 0; ++kkn; if (kkn == 4) { kkn = 0; icn += 64; } }
                }
                int va = (ml + dx) * 72 + kk * 16 + kh * 8;
                #pragma unroll
                for (int r = 0; r < 6; ++r) {
                    short8 Bf = *(const short8*)&Xs[r * 2520 + va];
                    if (r <= 3)
                        acc[r]     = __builtin_amdgcn_mfma_f32_32x32x16_bf16(Acur0, Bf, acc[r], 0, 0, 0);
                    if (r >= 1 && r <= 4)
                        acc[r - 1] = __builtin_amdgcn_mfma_f32_32x32x16_bf16(Acur1, Bf, acc[r - 1], 0, 0, 0);
                    if (r >= 2)
                        acc[r - 2] = __builtin_amdgcn_mfma_f32_32x32x16_bf16(Acur2, Bf, acc[r - 2], 0, 0, 0);
                }
                Acur0 = Anext0; Acur1 = Anext1; Acur2 = Anext2;
            }
        }
    }

    // epilogue: D layout col=lane&31, row=(reg&3)+8*(reg>>2)+4*(lane>>5); mask rows >= 28
    if (ml < W_) {
        #pragma unroll
        for (int j = 0; j < 4; ++j) {
            if (py0 + j < H_) {
                float* op = out + ((size_t)(b * COUT_ + oc0 + w * 32)) * HW_ + (py0 + j) * W_ + ml;
                #pragma unroll
                for (int r = 0; r < 16; ++r) {
                    int ocd = (r & 3) + 8 * (r >> 2) + 4 * kh;
                    op[(size_t)ocd * HW_] = acc[j][r];
                }
            }
        }
    }
}

// ---------------- Fallback path (ws too small): fp32 direct ----------------
__global__ __launch_bounds__(256) void pool_kernel(const float* __restrict__ x,
                                                   float* __restrict__ pooled) {
    int w = blockIdx.x * 4 + (threadIdx.x >> 6);
    int lane = threadIdx.x & 63;
    const float* p = x + (size_t)w * HW_;
    float s = 0.f;
    for (int i = lane; i < HW_; i += 64) s += p[i];
    for (int off = 32; off; off >>= 1) s += __shfl_down(s, off);
    if (lane == 0) pooled[w] = s * (1.0f / HW_);
}

__global__ __launch_bounds__(256) void se2_kernel(const float* __restrict__ pooled,
                                                  const float* __restrict__ fc1_w,
                                                  const float* __restrict__ fc2_w,
                                                  const float* __restrict__ fc2_b,
                                                  float* __restrict__ prob) {
    __shared__ float pl[CIN_];
    __shared__ float h[HID_];
    __shared__ float wb[16640];
    int b = blockIdx.x, t = threadIdx.x;
    pl[t] = pooled[b * CIN_ + t];
    #pragma unroll
    for (int i = 0; i < 16; ++i) {
        int l = t + i * 256;
        float4 v = *(const float4*)(fc1_w + (size_t)l * 4);
        int r = l >> 6, cc = (l & 63) * 4;
        float* dst = &wb[r * 257 + cc];
        dst[0] = v.x; dst[1] = v.y; dst[2] = v.z; dst[3] = v.w;
    }
    __syncthreads();
    if (t < HID_) {
        float s = 0.f;
        const float* wr = &wb[t * 257];
        for (int c = 0; c < CIN_; ++c) s += pl[c] * wr[c];
        h[t] = fmaxf(s, 0.f);
    }
    float yk[KEXP_];
    for (int k = 0; k < KEXP_; ++k) {
        __syncthreads();
        #pragma unroll
        for (int i = 0; i < 16; ++i) {
            int l = t + i * 256;
            float4 v = *(const float4*)(fc2_w + (size_t)k * COUT_ * HID_ + (size_t)l * 4);
            int o = l >> 4, jj = (l & 15) * 4;
            float* dst = &wb[o * 65 + jj];
            dst[0] = v.x; dst[1] = v.y; dst[2] = v.z; dst[3] = v.w;
        }
        __syncthreads();
        float s = fc2_b[k * COUT_ + t];
        const float* wr = &wb[t * 65];
        #pragma unroll
        for (int j = 0; j < HID_; ++j) s += h[j] * wr[j];
        yk[k] = s * 0.125f;
    }
    float m = yk[0];
    for (int k = 1; k < KEXP_; ++k) m = fmaxf(m, yk[k]);
    float e[KEXP_], sum = 0.f;
    for (int k = 0; k < KEXP_; ++k) { e[k] = expf(yk[k] - m); sum += e[k]; }
    float inv = 1.0f / sum;
    for (int k = 0; k < KEXP_; ++k)
        prob[b * (KEXP_ * COUT_) + k * COUT_ + t] = e[k] * inv;
}

__global__ __launch_bounds__(256) void conv_kernel(const float* __restrict__ x,
                                                   const float* __restrict__ weight,
                                                   const float* __restrict__ prob,
                                                   float* __restrict__ out) {
    __shared__ float xs[30 * 30];
    __shared__ float wagg[8][32][12];
    __shared__ float pl[KEXP_][8];

    int b  = blockIdx.x >> 5;
    int o0 = (blockIdx.x & 31) * 8;
    int t  = threadIdx.x;

    if (t < 32) {
        int k = t >> 3, oc = t & 7;
        pl[k][oc] = prob[b * (KEXP_ * COUT_) + k * COUT_ + o0 + oc];
    }
    int p0 = t;
    int pr[4], pc[4];
    bool pv[4];
    #pragma unroll
    for (int j = 0; j < 4; ++j) {
        int p = p0 + j * 256;
        pv[j] = p < HW_;
        pr[j] = p / W_;
        pc[j] = p % W_;
    }
    float acc[8][4];
    #pragma unroll
    for (int oc = 0; oc < 8; ++oc)
        #pragma unroll
        for (int j = 0; j < 4; ++j) acc[oc][j] = 0.f;

    int aoc = t >> 5, aii = t & 31;

    for (int ic0 = 0; ic0 < CIN_; ic0 += 32) {
        __syncthreads();
        {
            float w9[9];
            #pragma unroll
            for (int j = 0; j < 9; ++j) w9[j] = 0.f;
            int i = ic0 + aii;
            #pragma unroll
            for (int k = 0; k < KEXP_; ++k) {
                float pk = pl[k][aoc];
                const float* wp = weight + ((size_t)(k * COUT_ + o0 + aoc) * CIN_ + i) * 9;
                #pragma unroll
                for (int j = 0; j < 9; ++j) w9[j] += pk * wp[j];
            }
            #pragma unroll
            for (int j = 0; j < 9; ++j) wagg[aoc][aii][j] = w9[j];
        }
        for (int ii = 0; ii < 32; ++ii) {
            int i = ic0 + ii;
            __syncthreads();
            const float* xp = x + (size_t)(b * CIN_ + i) * HW_;
            for (int e = t; e < 900; e += 256) {
                int ry = e / 30, cx = e - ry * 30;
                int gy = ry - 1, gx = cx - 1;
                float v = 0.f;
                if ((unsigned)gy < 28u && (unsigned)gx < 28u) v = xp[gy * W_ + gx];
                xs[e] = v;
            }
            __syncthreads();
            float xv[4][9];
            #pragma unroll
            for (int j = 0; j < 4; ++j) {
                if (pv[j]) {
                    const float* xr = &xs[pr[j] * 30 + pc[j]];
                    xv[j][0] = xr[0];  xv[j][1] = xr[1];  xv[j][2] = xr[2];
                    xv[j][3] = xr[30]; xv[j][4] = xr[31]; xv[j][5] = xr[32];
                    xv[j][6] = xr[60]; xv[j][7] = xr[61]; xv[j][8] = xr[62];
                } else {
                    #pragma unroll
                    for (int q = 0; q < 9; ++q) xv[j][q] = 0.f;
                }
            }
            #pragma unroll
            for (int oc = 0; oc < 8; ++oc) {
                float4 wa = *(const float4*)&wagg[oc][ii][0];
                float4 wb2 = *(const float4*)&wagg[oc][ii][4];
                float  wc = wagg[oc][ii][8];
                #pragma unroll
                for (int j = 0; j < 4; ++j) {
                    acc[oc][j] += xv[j][0] * wa.x + xv[j][1] * wa.y + xv[j][2] * wa.z
                                + xv[j][3] * wa.w + xv[j][4] * wb2.x + xv[j][5] * wb2.y
                                + xv[j][6] * wb2.z + xv[j][7] * wb2.w + xv[j][8] * wc;
                }
            }
        }
    }
    #pragma unroll
    for (int oc = 0; oc < 8; ++oc) {
        float* op = out + (size_t)(b * COUT_ + o0 + oc) * HW_ + p0;
        #pragma unroll
        for (int j = 0; j < 4; ++j)
            if (pv[j]) op[j * 256] = acc[oc][j];
    }
}

extern "C" void kernel_launch(void* const* d_in, const int* in_sizes, int n_in,
                              void* d_out, int out_size, void* d_ws, size_t ws_size,
                              hipStream_t stream) {
    const float* x     = (const float*)d_in[0];
    const float* fc1_w = (const float*)d_in[1];
    const float* fc2_w = (const float*)d_in[2];
    const float* fc2_b = (const float*)d_in[3];
    const float* weight= (const float*)d_in[4];
    float* out = (float*)d_out;

    char* ws = (char*)d_ws;
    // layout: partial @0 (819200) | fc1T @819200 (65536) | x_t @884736 (12845056) | agg @13729792 (37748736)
    float* partial = (float*)(ws);
    float* fc1T    = (float*)(ws + 819200);
    unsigned short* x_t = (unsigned short*)(ws + 884736);
    unsigned short* agg = (unsigned short*)(ws + 13729792);
    const size_t WS_NEED = 13729792 + 37748736;   // 51,478,528

    if (ws_size >= WS_NEED) {
        xpose2_kernel<<<3200, 256, 0, stream>>>(x, fc1_w, x_t, partial, fc1T);
        agg8_kernel<<<512, 256, 0, stream>>>(weight, partial, fc1T, fc2_w, fc2_b, agg);
        conv7_kernel<<<512, 256, 0, stream>>>(x_t, agg, out);
    } else {
        float* prob = (float*)(ws);
        float* pooled = (float*)(ws + 131072);
        pool_kernel<<<(B_ * CIN_) / 4, 256, 0, stream>>>(x, pooled);
        se2_kernel<<<B_, 256, 0, stream>>>(pooled, fc1_w, fc2_w, fc2_b, prob);
        conv_kernel<<<B_ * (COUT_ / 8), 256, 0, stream>>>(x, weight, prob, out);
    }
}